// Round 1
// 318.976 us; speedup vs baseline: 1.1281x; 1.1281x over previous
//
#include <hip/hip_runtime.h>
#include <math.h>

#define BB 32
#define MM 2048
#define KK 4
#define EE 128
#define GG 128
#define VV 50000
#define HOPS 3

// ---------------- GRU cell: one block per batch row; also zeroes o1 ----------------
__global__ __launch_bounds__(384) void gru_kernel(
    const float* __restrict__ emb0,   // emb table 0 [V][E]
    const int*   __restrict__ y,      // [B]
    const float* __restrict__ hprev,  // [B][G]
    const float* __restrict__ W_ih,   // [3G][E]
    const float* __restrict__ W_hh,   // [3G][G]
    const float* __restrict__ b_ih,   // [3G]
    const float* __restrict__ b_hh,   // [3G]
    float* __restrict__ h_out,        // d_out [B][G]
    float* __restrict__ q,            // ws    [B][G]
    float* __restrict__ o1)           // ws    [B][E] -> zeroed here (atomics later)
{
    int b = blockIdx.x;
    int t = threadIdx.x;
    __shared__ float x[EE], h[GG], gi[3*GG], gh[3*GG];
    if (t < EE)            x[t]       = emb0[(size_t)y[b]*EE + t];
    else if (t < 2*EE)     h[t-EE]    = hprev[b*GG + (t-EE)];
    if (t < EE) o1[b*EE + t] = 0.f;
    __syncthreads();
    {
        float accI = b_ih[t], accH = b_hh[t];
        const float* wi = W_ih + (size_t)t*EE;
        const float* wh = W_hh + (size_t)t*GG;
        #pragma unroll 8
        for (int e = 0; e < EE; e++) { accI += x[e]*wi[e]; accH += h[e]*wh[e]; }
        gi[t] = accI; gh[t] = accH;
    }
    __syncthreads();
    if (t < GG) {
        float r = 1.f/(1.f + __expf(-(gi[t]        + gh[t])));
        float z = 1.f/(1.f + __expf(-(gi[GG+t]     + gh[GG+t])));
        float n = tanhf(gi[2*GG+t] + r*gh[2*GG+t]);
        float hn = (1.f - z)*n + z*h[t];
        h_out[b*GG + t] = hn;
        q[b*GG + t]     = hn;
    }
}

// ---------------- attention scores (gather variant, hop 0 only) ----------------
__global__ __launch_bounds__(256) void scores_kernel(
    const float* __restrict__ embT,   // emb table 0
    const int*   __restrict__ ctx,    // [B][M][K]
    const float* __restrict__ q,      // [B][E]
    float* __restrict__ p)            // [B][M]
{
    int gid  = blockIdx.x * 4 + (threadIdx.x >> 6);  // == b*M + m
    int lane = threadIdx.x & 63;
    int b    = gid >> 11;                            // /M (M=2048)
    const int4 c = *(const int4*)(ctx + (size_t)gid*KK);
    float2 qv = *(const float2*)(q + b*EE + lane*2);
    float2 v0 = *(const float2*)(embT + (size_t)c.x*EE + lane*2);
    float2 v1 = *(const float2*)(embT + (size_t)c.y*EE + lane*2);
    float2 v2 = *(const float2*)(embT + (size_t)c.z*EE + lane*2);
    float2 v3 = *(const float2*)(embT + (size_t)c.w*EE + lane*2);
    float sx = v0.x + v1.x + v2.x + v3.x;
    float sy = v0.y + v1.y + v2.y + v3.y;
    float acc = sx*qv.x + sy*qv.y;
    #pragma unroll
    for (int off = 32; off; off >>= 1) acc += __shfl_down(acc, off);
    if (lane == 0) p[gid] = acc;
}

// ---------------- attention scores (streamed S variant, hops 1..2) ----------------
// S[b][m][e] = sum_k emb[hop][ctx[b,m,k]][e] was written coalesced by the previous
// hop's oacc pass (weight tying: C-table of hop h == A-table of hop h+1).
// 33.5 MB stream read instead of 128 MB random gather.
__global__ __launch_bounds__(256) void scores_s_kernel(
    const float* __restrict__ S,      // [B*M][E]
    const float* __restrict__ q,      // [B][E]
    float* __restrict__ p)            // [B][M]
{
    int gid  = blockIdx.x * 4 + (threadIdx.x >> 6);
    int lane = threadIdx.x & 63;
    int b    = gid >> 11;
    float2 sv = *(const float2*)(S + (size_t)gid*EE + lane*2);
    float2 qv = *(const float2*)(q + b*EE + lane*2);
    float acc = sv.x*qv.x + sv.y*qv.y;
    #pragma unroll
    for (int off = 32; off; off >>= 1) acc += __shfl_down(acc, off);
    if (lane == 0) p[gid] = acc;
}

// ---------------- fused: softmax stats + weighted memory read + q update ----------------
// One block per (b, slot-chunk-of-64). Each block independently recomputes the row's
// softmax stats from p (8 KB read, ~6% of its 128 KB gather), gathers the C-table rows,
// optionally writes the row-sums S for the next hop's streamed scores, and atomically
// accumulates its o-partial into q (and o1 for hop 0).
template<int WRITE_S, int SAVE_O1>
__global__ __launch_bounds__(256) void oacc_fused_kernel(
    const float* __restrict__ embT,   // emb + (hop+1)*V*E
    const int*   __restrict__ ctx,    // [B][M][K]
    const float* __restrict__ p,      // [B][M] raw scores
    float* __restrict__ S_out,        // [B*M][E] row sums (if WRITE_S)
    float* __restrict__ q,            // [B][E] atomic +=
    float* __restrict__ o1)           // [B][E] atomic += (if SAVE_O1)
{
    int blk = blockIdx.x;             // b*32 + s
    int b = blk >> 5, s = blk & 31;
    int t = threadIdx.x;
    int w = t >> 6, lane = t & 63;

    // --- softmax stats over p[b][:] (all 2048) ---
    const float* row = p + (size_t)b*MM;
    float v[8];
    float mx = -INFINITY;
    #pragma unroll
    for (int i = 0; i < 8; i++) { v[i] = row[t + i*256]; mx = fmaxf(mx, v[i]); }
    __shared__ float red[6];
    #pragma unroll
    for (int off = 32; off; off >>= 1) mx = fmaxf(mx, __shfl_down(mx, off));
    if (lane == 0) red[w] = mx;
    __syncthreads();
    if (t == 0) red[4] = fmaxf(fmaxf(red[0],red[1]), fmaxf(red[2],red[3]));
    __syncthreads();
    mx = red[4];
    float sum = 0.f;
    #pragma unroll
    for (int i = 0; i < 8; i++) sum += __expf(v[i] - mx);
    #pragma unroll
    for (int off = 32; off; off >>= 1) sum += __shfl_down(sum, off);
    __syncthreads();
    if (lane == 0) red[w] = sum;
    __syncthreads();
    if (t == 0) red[5] = 1.f / (red[0]+red[1]+red[2]+red[3]);
    __syncthreads();
    float rs = red[5];

    // --- gather + (optional S write) + weighted accumulate ---
    int m0 = s*64 + w*16;
    float ax = 0.f, ay = 0.f;
    for (int i = 0; i < 16; i++) {
        int m = m0 + i;
        float a = __expf(row[m] - mx) * rs;
        const int4 c = *(const int4*)(ctx + (size_t)(b*MM + m)*KK);
        float2 v0 = *(const float2*)(embT + (size_t)c.x*EE + lane*2);
        float2 v1 = *(const float2*)(embT + (size_t)c.y*EE + lane*2);
        float2 v2 = *(const float2*)(embT + (size_t)c.z*EE + lane*2);
        float2 v3 = *(const float2*)(embT + (size_t)c.w*EE + lane*2);
        float sx = v0.x + v1.x + v2.x + v3.x;
        float sy = v0.y + v1.y + v2.y + v3.y;
        if (WRITE_S)
            *(float2*)(S_out + ((size_t)b*MM + m)*EE + lane*2) = make_float2(sx, sy);
        ax += a * sx;
        ay += a * sy;
    }
    __shared__ float acc_red[4][EE];
    acc_red[w][lane*2]   = ax;
    acc_red[w][lane*2+1] = ay;
    __syncthreads();
    if (t < EE) {
        float vv = acc_red[0][t] + acc_red[1][t] + acc_red[2][t] + acc_red[3][t];
        atomicAdd(&q[b*EE + t], vv);
        if (SAVE_O1) atomicAdd(&o1[b*EE + t], vv);
    }
}

// ---------------- softmax over M: writes final attn output (hop 2 only) ----------------
__global__ __launch_bounds__(256) void softmax_m_kernel(
    const float* __restrict__ p,      // [B][M]
    float* __restrict__ attn)         // [B][M]
{
    int b = blockIdx.x, t = threadIdx.x;
    const float* row = p + (size_t)b*MM;
    float v[8];
    float mx = -INFINITY;
    #pragma unroll
    for (int i = 0; i < 8; i++) { v[i] = row[t + i*256]; mx = fmaxf(mx, v[i]); }
    __shared__ float red[6];
    int w = t >> 6, lane = t & 63;
    #pragma unroll
    for (int off = 32; off; off >>= 1) mx = fmaxf(mx, __shfl_down(mx, off));
    if (lane == 0) red[w] = mx;
    __syncthreads();
    if (t == 0) { float m2 = fmaxf(fmaxf(red[0],red[1]), fmaxf(red[2],red[3])); red[4] = m2; }
    __syncthreads();
    mx = red[4];
    float sum = 0.f;
    #pragma unroll
    for (int i = 0; i < 8; i++) { v[i] = __expf(v[i] - mx); sum += v[i]; }
    #pragma unroll
    for (int off = 32; off; off >>= 1) sum += __shfl_down(sum, off);
    if (lane == 0) red[w] = sum;
    __syncthreads();
    if (t == 0) { red[5] = 1.f / (red[0]+red[1]+red[2]+red[3]); }
    __syncthreads();
    float rs = red[5];
    #pragma unroll
    for (int i = 0; i < 8; i++) attn[(size_t)b*MM + t + i*256] = v[i]*rs;
}

// ---------------- vocab logits: 50000x32x256 GEMM, 4v x 4b register tile ----------------
__global__ __launch_bounds__(256) void logits_kernel(
    const float* __restrict__ h,      // [B][G] (from d_out)
    const float* __restrict__ o1,     // [B][E] (ws)
    const float* __restrict__ Wv,     // [V][256]
    const float* __restrict__ bv,     // [V]
    float* __restrict__ logits)       // [B][V] (d_out p_vocab region)
{
    __shared__ float Ut[256][32];     // [e][b]
    __shared__ float Wt[32][132];     // [e_local][v_local], pad 128->132
    int t = threadIdx.x;
    for (int i = t; i < 256*32; i += 256) {
        int e = i >> 5, b = i & 31;
        Ut[e][b] = (e < GG) ? h[b*GG + e] : o1[b*EE + (e - GG)];
    }
    int vg = t & 31;
    int bg = t >> 5;
    int v0 = blockIdx.x * 128;
    float acc[4][4];
    #pragma unroll
    for (int i = 0; i < 4; i++)
        #pragma unroll
        for (int j = 0; j < 4; j++) acc[i][j] = 0.f;

    int vrow = t >> 1;
    int half = t & 1;
    const float* wrow = Wv + (size_t)(v0 + vrow)*256 + half*16;
    bool vok = (v0 + vrow) < VV;

    for (int ec = 0; ec < 256; ec += 32) {
        __syncthreads();
        #pragma unroll
        for (int j = 0; j < 4; j++) {
            float4 w = make_float4(0.f, 0.f, 0.f, 0.f);
            if (vok) w = *(const float4*)(wrow + ec + j*4);
            int e0 = half*16 + j*4;
            Wt[e0+0][vrow] = w.x;
            Wt[e0+1][vrow] = w.y;
            Wt[e0+2][vrow] = w.z;
            Wt[e0+3][vrow] = w.w;
        }
        __syncthreads();
        #pragma unroll 8
        for (int e = 0; e < 32; e++) {
            float4 w = *(const float4*)(&Wt[e][vg*4]);
            float4 u = *(const float4*)(&Ut[ec + e][bg*4]);
            acc[0][0] += w.x*u.x; acc[0][1] += w.x*u.y; acc[0][2] += w.x*u.z; acc[0][3] += w.x*u.w;
            acc[1][0] += w.y*u.x; acc[1][1] += w.y*u.y; acc[1][2] += w.y*u.z; acc[1][3] += w.y*u.w;
            acc[2][0] += w.z*u.x; acc[2][1] += w.z*u.y; acc[2][2] += w.z*u.z; acc[2][3] += w.z*u.w;
            acc[3][0] += w.w*u.x; acc[3][1] += w.w*u.y; acc[3][2] += w.w*u.z; acc[3][3] += w.w*u.w;
        }
    }
    #pragma unroll
    for (int i = 0; i < 4; i++) {
        int v = v0 + vg*4 + i;
        if (v < VV) {
            float bb = bv[v];
            #pragma unroll
            for (int j = 0; j < 4; j++)
                logits[(size_t)(bg*4 + j)*VV + v] = acc[i][j] + bb;
        }
    }
}

// ---------------- vocab softmax partial stats: 8 chunks per batch row ----------------
#define VCHUNK 6250
__global__ __launch_bounds__(256) void vpart_kernel(
    const float* __restrict__ logits, // [B][V]
    float* __restrict__ part)         // [B][8][2] = {max, sumexp}
{
    int blk = blockIdx.x;             // b*8 + c
    int b = blk >> 3, c = blk & 7;
    int t = threadIdx.x;
    const float* row = logits + (size_t)b*VV;
    int start = c*VCHUNK;
    int end   = min(start + VCHUNK, VV);
    __shared__ float red[4];
    int w = t >> 6, lane = t & 63;
    float mx = -INFINITY;
    for (int i = start + t; i < end; i += 256) mx = fmaxf(mx, row[i]);
    #pragma unroll
    for (int off = 32; off; off >>= 1) mx = fmaxf(mx, __shfl_down(mx, off));
    if (lane == 0) red[w] = mx;
    __syncthreads();
    float m = fmaxf(fmaxf(red[0], red[1]), fmaxf(red[2], red[3]));
    float sum = 0.f;
    for (int i = start + t; i < end; i += 256) sum += __expf(row[i] - m);
    #pragma unroll
    for (int off = 32; off; off >>= 1) sum += __shfl_down(sum, off);
    __syncthreads();
    if (lane == 0) red[w] = sum;
    __syncthreads();
    if (t == 0) {
        part[blk*2]   = m;
        part[blk*2+1] = red[0] + red[1] + red[2] + red[3];
    }
}

// ---------------- finalize p_vocab in place ----------------
__global__ __launch_bounds__(256) void vfinal_kernel(
    float* __restrict__ logits,       // [B][V], in-place
    const float* __restrict__ part)   // [B][8][2]
{
    int i = blockIdx.x*256 + threadIdx.x;
    if (i >= BB*VV) return;
    int b = i / VV;
    const float* pp = part + b*16;
    float M = -INFINITY;
    #pragma unroll
    for (int c = 0; c < 8; c++) M = fmaxf(M, pp[c*2]);
    float S = 0.f;
    #pragma unroll
    for (int c = 0; c < 8; c++) S += pp[c*2+1] * __expf(pp[c*2] - M);
    logits[i] = __expf(logits[i] - M) * (1.f / S);
}

extern "C" void kernel_launch(void* const* d_in, const int* in_sizes, int n_in,
                              void* d_out, int out_size, void* d_ws, size_t ws_size,
                              hipStream_t stream) {
    const int*   ctx    = (const int*)  d_in[0];
    const float* h_prev = (const float*)d_in[1];
    const int*   y      = (const int*)  d_in[2];
    const float* emb    = (const float*)d_in[3];
    const float* W_ih   = (const float*)d_in[4];
    const float* W_hh   = (const float*)d_in[5];
    const float* b_ih   = (const float*)d_in[6];
    const float* b_hh   = (const float*)d_in[7];
    const float* Wv     = (const float*)d_in[8];
    const float* bv     = (const float*)d_in[9];

    float* out_h    = (float*)d_out;                 // [B][G]
    float* out_pv   = out_h + BB*GG;                 // [B][V]
    float* out_attn = out_pv + (size_t)BB*VV;        // [B][M]

    float* ws   = (float*)d_ws;
    float* q    = ws;                       // 4096
    float* o1   = q + BB*EE;                // 4096
    float* p    = o1 + BB*EE;               // 65536
    float* S    = p + BB*MM;                // 8388608 (33.5 MB, reused across hops)
    float* part = S + (size_t)BB*MM*EE;     // 512

    // GRU (seeds q=h, zeroes o1 for atomic accumulation)
    gru_kernel<<<BB, 384, 0, stream>>>(emb, y, h_prev, W_ih, W_hh, b_ih, b_hh, out_h, q, o1);

    // hop 0: gather scores on table0; fused softmax+read on table1, write S1, q+=o, o1+=o
    scores_kernel<<<(BB*MM)/4, 256, 0, stream>>>(emb, ctx, q, p);
    oacc_fused_kernel<1,1><<<BB*32, 256, 0, stream>>>(
        emb + (size_t)1*VV*EE, ctx, p, S, q, o1);

    // hop 1: streamed scores from S1; fused softmax+read on table2, write S2, q+=o
    scores_s_kernel<<<(BB*MM)/4, 256, 0, stream>>>(S, q, p);
    oacc_fused_kernel<1,0><<<BB*32, 256, 0, stream>>>(
        emb + (size_t)2*VV*EE, ctx, p, S, q, nullptr);

    // hop 2: streamed scores from S2; only attn = softmax(p) is observable
    // (o/q at hop 2 are dead in the reference -> table3 gather eliminated)
    scores_s_kernel<<<(BB*MM)/4, 256, 0, stream>>>(S, q, p);
    softmax_m_kernel<<<BB, 256, 0, stream>>>(p, out_attn);

    // vocab head
    logits_kernel<<<(VV + 127)/128, 256, 0, stream>>>(out_h, o1, Wv, bv, out_pv);
    vpart_kernel<<<BB*8, 256, 0, stream>>>(out_pv, part);
    vfinal_kernel<<<(BB*VV + 255)/256, 256, 0, stream>>>(out_pv, part);
}